// Round 6
// baseline (54268.628 us; speedup 1.0000x reference)
//
#include <hip/hip_runtime.h>
#include <hip/hip_bf16.h>

typedef __attribute__((ext_vector_type(4))) float f32x4;
typedef __attribute__((ext_vector_type(8))) short bf16x8;
typedef unsigned short u16;

#define DEV static __device__ __forceinline__

DEV u16 f2bf(float f){
  unsigned v = __float_as_uint(f);
  v += 0x7fffu + ((v >> 16) & 1u);
  return (u16)(v >> 16);
}
DEV float bf2f(u16 u){ return __uint_as_float(((unsigned)u) << 16); }
DEV float sigm(float x){ return 1.0f / (1.0f + __expf(-x)); }
DEV float tanh_(float x){ return 1.0f - 2.0f / (__expf(2.0f * x) + 1.0f); }
DEV bf16x8 ld8(const u16* p){ return *(const bf16x8*)p; }
DEV float clip6(float v){ return fminf(fmaxf(v, -6.f), 6.f); }

template<int KIT, int NT>
DEV void mmK(const u16* ap, const u16* wp, int ldw, f32x4* acc){
  #pragma unroll 4
  for (int kk = 0; kk < KIT; ++kk){
    bf16x8 a = ld8(ap + kk * 32);
    #pragma unroll
    for (int nt = 0; nt < NT; ++nt){
      bf16x8 b = ld8(wp + (size_t)(nt * 16) * ldw + kk * 32);
      acc[nt] = __builtin_amdgcn_mfma_f32_16x16x32_bf16(a, b, acc[nt], 0, 0, 0);
    }
  }
}

// ---------------- prologue kernels (convert + phi_x precompute) ----------------
struct GemmDesc {
  const u16* A; const u16* W; const float* bias; u16* out;
  int lda, ldw, ldo, N, K;
};

__global__ __launch_bounds__(256) void k_gemm_pre(GemmDesc d){
  const int ntn = d.N >> 6;
  const int bm = blockIdx.x / ntn, bn = blockIdx.x - bm * ntn;
  const int w = threadIdx.x >> 6, lane = threadIdx.x & 63;
  const int r = lane & 15, g = lane >> 4;
  const int m0 = bm * 64 + w * 16, n0 = bn * 64;
  f32x4 acc[4];
  #pragma unroll
  for (int i = 0; i < 4; ++i) acc[i] = (f32x4){0.f, 0.f, 0.f, 0.f};
  const u16* ap = d.A + (size_t)(m0 + r) * d.lda + g * 8;
  const u16* wp = d.W + (size_t)(n0 + r) * d.ldw + g * 8;
  for (int k = 0; k < d.K; k += 32){
    bf16x8 a = ld8(ap + k);
    #pragma unroll
    for (int nt = 0; nt < 4; ++nt){
      bf16x8 b = ld8(wp + (size_t)(nt * 16) * d.ldw + k);
      acc[nt] = __builtin_amdgcn_mfma_f32_16x16x32_bf16(a, b, acc[nt], 0, 0, 0);
    }
  }
  #pragma unroll
  for (int nt = 0; nt < 4; ++nt)
    #pragma unroll
    for (int i = 0; i < 4; ++i){
      const int row = m0 + g * 4 + i, col = n0 + nt * 16 + r;
      float v = fmaxf(acc[nt][i] + d.bias[col], 0.f);
      d.out[(size_t)row * d.ldo + col] = f2bf(v);
    }
}

#define NCONV 19
struct ConvMulti { const float* src[NCONV]; u16* dst[NCONV]; int n[NCONV]; int total; };

__global__ __launch_bounds__(256) void k_convert(ConvMulti cm){
  const int stride = gridDim.x * blockDim.x;
  for (int i = blockIdx.x * blockDim.x + threadIdx.x; i < cm.total; i += stride){
    int idx = i, di = 0;
    while (idx >= cm.n[di]){ idx -= cm.n[di]; ++di; }
    cm.dst[di][idx] = f2bf(cm.src[di][idx]);
  }
}

// ---------------- the per-row-group full-recurrence kernel ----------------
// 16 blocks x 256 threads. Block b owns batch rows [16b, 16b+16) for ALL 128
// steps. All contractions are over the feature dim (row-local) -> no
// cross-block communication at all. Intermediates live in LDS; h0/h1
// ping-pong in global (same-CU coherence only).
struct Params {
  const u16 *phiX, *e1, *pr, *e2, *emu, *elv, *pmu, *plv, *pz, *d1, *ih0, *hh0, *ih1, *hh1, *d2, *dmu, *dlv;
  const float *b_e1, *b_pr, *b_e2, *b_emu, *b_elv, *b_pmu, *b_plv, *b_pz, *b_d1, *b_d2, *b_dmu, *b_dlv;
  const float *eps, *x;
  u16 *h0a, *h0b, *h1a, *h1b;
  float *accf; // [0..15] per-block KL, [16..31] per-block NLL
};

#define HP 520  // LDS row pitch in u16 (16B-aligned, bank-staggered)

__global__ __launch_bounds__(256, 1) void k_vrnn16(Params P)
{
  const int tid = threadIdx.x, w = tid >> 6, lane = tid & 63;
  const int r = lane & 15, g = lane >> 4;
  const int bid = blockIdx.x, m0 = bid * 16;
  const int n0w = w * 128;

  __shared__ u16 ench1_s[16 * HP], prih_s[16 * HP], phiz_s[16 * HP], dech1_s[16 * HP], dh_s[16 * HP];
  __shared__ float fbuf[4096];
  __shared__ u16 zs[16 * 72];
  __shared__ float red[256];
  float* qmu_s = fbuf;        float* qlv_s = fbuf + 1024;
  float* pmu_s = fbuf + 2048; float* plv_s = fbuf + 3072;
  float* dmu_s = fbuf;        float* dlv_s = fbuf + 2048; // time-disjoint alias

  float klacc = 0.f, nllacc = 0.f;

  for (int t = 0; t < 128; ++t){
    const u16* h1o = (t & 1) ? P.h1b : P.h1a;  u16* h1n = (t & 1) ? P.h1a : P.h1b;
    const u16* h0o = (t & 1) ? P.h0b : P.h0a;  u16* h0n = (t & 1) ? P.h0a : P.h0b;
    const u16* aX  = P.phiX + ((size_t)t * 256 + m0 + r) * 512 + g * 8;
    const u16* aH1 = h1o + (size_t)(m0 + r) * 512 + g * 8;
    const u16* aH0 = h0o + (size_t)(m0 + r) * 512 + g * 8;

    // P1: ench1 = relu([phiX_t | h1] @ e1^T + b)   [16,512], wave cols n0w..+128
    { f32x4 acc[8];
      #pragma unroll
      for (int i = 0; i < 8; ++i) acc[i] = (f32x4){0.f,0.f,0.f,0.f};
      mmK<16,8>(aX,  P.e1 + (size_t)(n0w + r) * 1024 + g * 8, 1024, acc);
      mmK<16,8>(aH1, P.e1 + (size_t)(n0w + r) * 1024 + 512 + g * 8, 1024, acc);
      #pragma unroll
      for (int nt = 0; nt < 8; ++nt)
        #pragma unroll
        for (int i = 0; i < 4; ++i){
          const int row = g * 4 + i, col = n0w + nt * 16 + r;
          ench1_s[row * HP + col] = f2bf(fmaxf(acc[nt][i] + P.b_e1[col], 0.f));
        }
    }
    // P2: prih = relu(h1 @ pr^T + b)
    { f32x4 acc[8];
      #pragma unroll
      for (int i = 0; i < 8; ++i) acc[i] = (f32x4){0.f,0.f,0.f,0.f};
      mmK<16,8>(aH1, P.pr + (size_t)(n0w + r) * 512 + g * 8, 512, acc);
      #pragma unroll
      for (int nt = 0; nt < 8; ++nt)
        #pragma unroll
        for (int i = 0; i < 4; ++i){
          const int row = g * 4 + i, col = n0w + nt * 16 + r;
          prih_s[row * HP + col] = f2bf(fmaxf(acc[nt][i] + P.b_pr[col], 0.f));
        }
    }
    __syncthreads();
    // P3: ench = relu(ench1 @ e2^T + b) -> dh_s
    { f32x4 acc[8];
      #pragma unroll
      for (int i = 0; i < 8; ++i) acc[i] = (f32x4){0.f,0.f,0.f,0.f};
      mmK<16,8>(ench1_s + r * HP + g * 8, P.e2 + (size_t)(n0w + r) * 512 + g * 8, 512, acc);
      #pragma unroll
      for (int nt = 0; nt < 8; ++nt)
        #pragma unroll
        for (int i = 0; i < 4; ++i){
          const int row = g * 4 + i, col = n0w + nt * 16 + r;
          dh_s[row * HP + col] = f2bf(fmaxf(acc[nt][i] + P.b_e2[col], 0.f));
        }
    }
    __syncthreads();
    // P4: one head per wave: qmu, qlv (from ench), pmu, plv (from prih)
    { f32x4 acc[4];
      #pragma unroll
      for (int i = 0; i < 4; ++i) acc[i] = (f32x4){0.f,0.f,0.f,0.f};
      const u16* A  = (w < 2) ? dh_s : prih_s;
      const u16* W_ = (w == 0) ? P.emu : (w == 1) ? P.elv : (w == 2) ? P.pmu : P.plv;
      const float* bs = (w == 0) ? P.b_emu : (w == 1) ? P.b_elv : (w == 2) ? P.b_pmu : P.b_plv;
      float* outp = (w == 0) ? qmu_s : (w == 1) ? qlv_s : (w == 2) ? pmu_s : plv_s;
      const bool cl = (w & 1);
      mmK<16,4>(A + r * HP + g * 8, W_ + (size_t)r * 512 + g * 8, 512, acc);
      #pragma unroll
      for (int nt = 0; nt < 4; ++nt)
        #pragma unroll
        for (int i = 0; i < 4; ++i){
          const int row = g * 4 + i, col = nt * 16 + r;
          float v = acc[nt][i] + bs[col];
          if (cl) v = clip6(v);
          outp[row * 64 + col] = v;
        }
    }
    __syncthreads();
    // z + KL accumulate (block rows only)
    { const float* epst = P.eps + (size_t)t * 16384 + (size_t)m0 * 64;
      for (int e = tid; e < 1024; e += 256){
        const int row = e >> 6, col = e & 63;
        const float qm = qmu_s[e], qv = qlv_s[e];
        const float pm = pmu_s[e], pv = plv_s[e];
        const float zv = qm + epst[row * 64 + col] * __expf(0.5f * qv);
        zs[row * 72 + col] = f2bf(zv);
        const float dm = qm - pm;
        klacc += 0.5f * (pv - qv + (__expf(qv) + dm * dm) * __expf(-pv) - 1.f);
      }
    }
    __syncthreads();
    // phiz = relu(z @ pz^T + b)
    { f32x4 acc[8];
      #pragma unroll
      for (int i = 0; i < 8; ++i) acc[i] = (f32x4){0.f,0.f,0.f,0.f};
      mmK<2,8>(zs + r * 72 + g * 8, P.pz + (size_t)(n0w + r) * 64 + g * 8, 64, acc);
      #pragma unroll
      for (int nt = 0; nt < 8; ++nt)
        #pragma unroll
        for (int i = 0; i < 4; ++i){
          const int row = g * 4 + i, col = n0w + nt * 16 + r;
          phiz_s[row * HP + col] = f2bf(fmaxf(acc[nt][i] + P.b_pz[col], 0.f));
        }
    }
    __syncthreads();
    // P5: dech1 = relu([phiz | h1] @ d1^T + b)
    { f32x4 acc[8];
      #pragma unroll
      for (int i = 0; i < 8; ++i) acc[i] = (f32x4){0.f,0.f,0.f,0.f};
      mmK<16,8>(phiz_s + r * HP + g * 8, P.d1 + (size_t)(n0w + r) * 1024 + g * 8, 1024, acc);
      mmK<16,8>(aH1, P.d1 + (size_t)(n0w + r) * 1024 + 512 + g * 8, 1024, acc);
      #pragma unroll
      for (int nt = 0; nt < 8; ++nt)
        #pragma unroll
        for (int i = 0; i < 4; ++i){
          const int row = g * 4 + i, col = n0w + nt * 16 + r;
          dech1_s[row * HP + col] = f2bf(fmaxf(acc[nt][i] + P.b_d1[col], 0.f));
        }
    }
    // P6: GRU layer 0: gi0 = [phiX_t | phiz] @ ih0^T, gh0 = h0 @ hh0^T, combine -> h0n
    { const u16* aZ = phiz_s + r * HP + g * 8;
      for (int j = 0; j < 2; ++j){
        f32x4 gi[3][4], gh[3][4];
        #pragma unroll
        for (int gt = 0; gt < 3; ++gt)
          #pragma unroll
          for (int i = 0; i < 4; ++i){ gi[gt][i] = (f32x4){0.f,0.f,0.f,0.f}; gh[gt][i] = (f32x4){0.f,0.f,0.f,0.f}; }
        #pragma unroll
        for (int gt = 0; gt < 3; ++gt){
          const u16* wih = P.ih0 + (size_t)(gt * 512 + n0w + j * 64 + r) * 1024 + g * 8;
          mmK<16,4>(aX, wih, 1024, gi[gt]);
          mmK<16,4>(aZ, wih + 512, 1024, gi[gt]);
          mmK<16,4>(aH0, P.hh0 + (size_t)(gt * 512 + n0w + j * 64 + r) * 512 + g * 8, 512, gh[gt]);
        }
        #pragma unroll
        for (int nt = 0; nt < 4; ++nt)
          #pragma unroll
          for (int i = 0; i < 4; ++i){
            const int row = g * 4 + i, c = n0w + j * 64 + nt * 16 + r;
            const float rr = sigm(gi[0][nt][i] + gh[0][nt][i]);
            const float zg = sigm(gi[1][nt][i] + gh[1][nt][i]);
            const float nn = tanh_(gi[2][nt][i] + rr * gh[2][nt][i]);
            const float hv = (1.f - zg) * nn + zg * bf2f(h0o[(size_t)(m0 + row) * 512 + c]);
            h0n[(size_t)(m0 + row) * 512 + c] = f2bf(hv);
          }
      }
    }
    __syncthreads();  // h0n visible (same CU; vmcnt drained at barrier)
    // P7: GRU layer 1: gi1 = h0n @ ih1^T, gh1 = h1 @ hh1^T, combine -> h1n
    { const u16* aH0n = h0n + (size_t)(m0 + r) * 512 + g * 8;
      for (int j = 0; j < 2; ++j){
        f32x4 gi[3][4], gh[3][4];
        #pragma unroll
        for (int gt = 0; gt < 3; ++gt)
          #pragma unroll
          for (int i = 0; i < 4; ++i){ gi[gt][i] = (f32x4){0.f,0.f,0.f,0.f}; gh[gt][i] = (f32x4){0.f,0.f,0.f,0.f}; }
        #pragma unroll
        for (int gt = 0; gt < 3; ++gt){
          mmK<16,4>(aH0n, P.ih1 + (size_t)(gt * 512 + n0w + j * 64 + r) * 512 + g * 8, 512, gi[gt]);
          mmK<16,4>(aH1,  P.hh1 + (size_t)(gt * 512 + n0w + j * 64 + r) * 512 + g * 8, 512, gh[gt]);
        }
        #pragma unroll
        for (int nt = 0; nt < 4; ++nt)
          #pragma unroll
          for (int i = 0; i < 4; ++i){
            const int row = g * 4 + i, c = n0w + j * 64 + nt * 16 + r;
            const float rr = sigm(gi[0][nt][i] + gh[0][nt][i]);
            const float zg = sigm(gi[1][nt][i] + gh[1][nt][i]);
            const float nn = tanh_(gi[2][nt][i] + rr * gh[2][nt][i]);
            const float hv = (1.f - zg) * nn + zg * bf2f(h1o[(size_t)(m0 + row) * 512 + c]);
            h1n[(size_t)(m0 + row) * 512 + c] = f2bf(hv);
          }
      }
    }
    __syncthreads();
    // P8: dech = relu(dech1 @ d2^T + b) -> dh_s (reuse)
    { f32x4 acc[8];
      #pragma unroll
      for (int i = 0; i < 8; ++i) acc[i] = (f32x4){0.f,0.f,0.f,0.f};
      mmK<16,8>(dech1_s + r * HP + g * 8, P.d2 + (size_t)(n0w + r) * 512 + g * 8, 512, acc);
      #pragma unroll
      for (int nt = 0; nt < 8; ++nt)
        #pragma unroll
        for (int i = 0; i < 4; ++i){
          const int row = g * 4 + i, col = n0w + nt * 16 + r;
          dh_s[row * HP + col] = f2bf(fmaxf(acc[nt][i] + P.b_d2[col], 0.f));
        }
    }
    __syncthreads();
    // dec heads: dmu / dlv  [16,128]
    { f32x4 acc[4];
      #pragma unroll
      for (int i = 0; i < 4; ++i) acc[i] = (f32x4){0.f,0.f,0.f,0.f};
      const bool isLv = (w >= 2); const int coff = (w & 1) * 64;
      const u16* W_ = isLv ? P.dlv : P.dmu;
      const float* bs = isLv ? P.b_dlv : P.b_dmu;
      mmK<16,4>(dh_s + r * HP + g * 8, W_ + (size_t)(coff + r) * 512 + g * 8, 512, acc);
      #pragma unroll
      for (int nt = 0; nt < 4; ++nt)
        #pragma unroll
        for (int i = 0; i < 4; ++i){
          const int row = g * 4 + i, col = coff + nt * 16 + r;
          float v = acc[nt][i] + bs[col];
          if (isLv) v = clip6(v);
          (isLv ? dlv_s : dmu_s)[row * 128 + col] = v;
        }
    }
    __syncthreads();
    // NLL accumulate
    { const float* xt = P.x + (size_t)t * 32768 + (size_t)m0 * 128;
      for (int e = tid; e < 2048; e += 256){
        const int row = e >> 7, col = e & 127;
        const float mu = dmu_s[e], lv = dlv_s[e];
        const float d = xt[row * 128 + col] - mu;
        nllacc += 0.5f * (lv + d * d * __expf(-lv));
      }
    }
    __syncthreads();
  }

  // per-block reductions -> plain stores (deterministic, no atomics)
  red[tid] = klacc;
  __syncthreads();
  for (int s = 128; s > 0; s >>= 1){ if (tid < s) red[tid] += red[tid + s]; __syncthreads(); }
  if (tid == 0) P.accf[bid] = red[0];
  __syncthreads();
  red[tid] = nllacc;
  __syncthreads();
  for (int s = 128; s > 0; s >>= 1){ if (tid < s) red[tid] += red[tid + s]; __syncthreads(); }
  if (tid == 0) P.accf[16 + bid] = red[0];
}

__global__ void k_final(const float* __restrict__ accf, float* __restrict__ out){
  if (threadIdx.x == 0 && blockIdx.x == 0){
    float kl = 0.f, rc = 0.f;
    for (int i = 0; i < 16; ++i){ kl += accf[i]; rc += accf[16 + i]; }
    kl *= (1.f / 32768.f);  // / B / T
    rc *= (1.f / 32768.f);
    out[0] = rc + kl; out[1] = rc; out[2] = kl;
  }
}

extern "C" void kernel_launch(void* const* d_in, const int* in_sizes, int n_in,
                              void* d_out, int out_size, void* d_ws, size_t ws_size,
                              hipStream_t stream)
{
  (void)in_sizes; (void)n_in; (void)out_size; (void)ws_size;
  const float* x     = (const float*)d_in[0];
  const float* eps   = (const float*)d_in[1];
  const float* w_px1 = (const float*)d_in[2];
  const float* b_px1 = (const float*)d_in[3];
  const float* w_px2 = (const float*)d_in[4];
  const float* b_px2 = (const float*)d_in[5];
  const float* w_pz  = (const float*)d_in[6];
  const float* b_pz  = (const float*)d_in[7];
  const float* w_e1  = (const float*)d_in[8];
  const float* b_e1  = (const float*)d_in[9];
  const float* w_e2  = (const float*)d_in[10];
  const float* b_e2  = (const float*)d_in[11];
  const float* w_emu = (const float*)d_in[12];
  const float* b_emu = (const float*)d_in[13];
  const float* w_elv = (const float*)d_in[14];
  const float* b_elv = (const float*)d_in[15];
  const float* w_pr  = (const float*)d_in[16];
  const float* b_pr  = (const float*)d_in[17];
  const float* w_pmu = (const float*)d_in[18];
  const float* b_pmu = (const float*)d_in[19];
  const float* w_plv = (const float*)d_in[20];
  const float* b_plv = (const float*)d_in[21];
  const float* w_d1  = (const float*)d_in[22];
  const float* b_d1  = (const float*)d_in[23];
  const float* w_d2  = (const float*)d_in[24];
  const float* b_d2  = (const float*)d_in[25];
  const float* w_dmu = (const float*)d_in[26];
  const float* b_dmu = (const float*)d_in[27];
  const float* w_dlv = (const float*)d_in[28];
  const float* b_dlv = (const float*)d_in[29];
  const float* w_ih0 = (const float*)d_in[30];
  const float* w_hh0 = (const float*)d_in[31];
  const float* w_ih1 = (const float*)d_in[32];
  const float* w_hh1 = (const float*)d_in[33];

  char* base = (char*)d_ws;
  size_t off = 0;
  auto alloc = [&](size_t bytes)->char*{
    char* p = base + off;
    off = (off + bytes + 255) & ~(size_t)255;
    return p;
  };
  u16* xbf    = (u16*)alloc((size_t)4194304 * 2);
  u16* cb_px1 = (u16*)alloc((size_t)65536 * 2);
  u16* cb_px2 = (u16*)alloc((size_t)262144 * 2);
  u16* cb_pz  = (u16*)alloc((size_t)32768 * 2);
  u16* cb_e1  = (u16*)alloc((size_t)524288 * 2);
  u16* cb_e2  = (u16*)alloc((size_t)262144 * 2);
  u16* cb_emu = (u16*)alloc((size_t)32768 * 2);
  u16* cb_elv = (u16*)alloc((size_t)32768 * 2);
  u16* cb_pr  = (u16*)alloc((size_t)262144 * 2);
  u16* cb_pmu = (u16*)alloc((size_t)32768 * 2);
  u16* cb_plv = (u16*)alloc((size_t)32768 * 2);
  u16* cb_d1  = (u16*)alloc((size_t)524288 * 2);
  u16* cb_d2  = (u16*)alloc((size_t)262144 * 2);
  u16* cb_dmu = (u16*)alloc((size_t)65536 * 2);
  u16* cb_dlv = (u16*)alloc((size_t)65536 * 2);
  u16* cb_ih0 = (u16*)alloc((size_t)1572864 * 2);
  u16* cb_hh0 = (u16*)alloc((size_t)786432 * 2);
  u16* cb_ih1 = (u16*)alloc((size_t)786432 * 2);
  u16* cb_hh1 = (u16*)alloc((size_t)786432 * 2);
  u16* phiX   = (u16*)alloc((size_t)16777216 * 2);
  u16* phiX1  = (u16*)alloc((size_t)16777216 * 2);
  u16* h0a = (u16*)alloc((size_t)131072 * 2);
  u16* h0b = (u16*)alloc((size_t)131072 * 2);
  u16* h1a = (u16*)alloc((size_t)131072 * 2);
  u16* h1b = (u16*)alloc((size_t)131072 * 2);
  float* accf = (float*)alloc(256);

  // zero h state (4 contiguous buffers of 262144 B each)
  hipMemsetAsync(h0a, 0, (size_t)4 * 262144, stream);

  // convert x + weights to bf16
  ConvMulti cm; int ci = 0, tot = 0;
  auto addc = [&](const float* s, u16* d, int n){ cm.src[ci] = s; cm.dst[ci] = d; cm.n[ci] = n; ++ci; tot += n; };
  addc(x, xbf, 4194304);
  addc(w_px1, cb_px1, 65536);   addc(w_px2, cb_px2, 262144);
  addc(w_pz,  cb_pz,  32768);   addc(w_e1,  cb_e1,  524288);
  addc(w_e2,  cb_e2,  262144);  addc(w_emu, cb_emu, 32768);
  addc(w_elv, cb_elv, 32768);   addc(w_pr,  cb_pr,  262144);
  addc(w_pmu, cb_pmu, 32768);   addc(w_plv, cb_plv, 32768);
  addc(w_d1,  cb_d1,  524288);  addc(w_d2,  cb_d2,  262144);
  addc(w_dmu, cb_dmu, 65536);   addc(w_dlv, cb_dlv, 65536);
  addc(w_ih0, cb_ih0, 1572864); addc(w_hh0, cb_hh0, 786432);
  addc(w_ih1, cb_ih1, 786432);  addc(w_hh1, cb_hh1, 786432);
  cm.total = tot;
  k_convert<<<2048, 256, 0, stream>>>(cm);

  { // precompute phi_x over all T*B rows
    GemmDesc d1g;
    d1g.A = xbf; d1g.W = cb_px1; d1g.bias = b_px1; d1g.out = phiX1;
    d1g.lda = 128; d1g.ldw = 128; d1g.ldo = 512; d1g.N = 512; d1g.K = 128;
    k_gemm_pre<<<512 * 8, 256, 0, stream>>>(d1g);
    GemmDesc d2g;
    d2g.A = phiX1; d2g.W = cb_px2; d2g.bias = b_px2; d2g.out = phiX;
    d2g.lda = 512; d2g.ldw = 512; d2g.ldo = 512; d2g.N = 512; d2g.K = 512;
    k_gemm_pre<<<512 * 8, 256, 0, stream>>>(d2g);
  }

  Params prm;
  prm.phiX = phiX;
  prm.e1 = cb_e1; prm.pr = cb_pr; prm.e2 = cb_e2;
  prm.emu = cb_emu; prm.elv = cb_elv; prm.pmu = cb_pmu; prm.plv = cb_plv;
  prm.pz = cb_pz; prm.d1 = cb_d1; prm.ih0 = cb_ih0; prm.hh0 = cb_hh0;
  prm.ih1 = cb_ih1; prm.hh1 = cb_hh1; prm.d2 = cb_d2;
  prm.dmu = cb_dmu; prm.dlv = cb_dlv;
  prm.b_e1 = b_e1; prm.b_pr = b_pr; prm.b_e2 = b_e2;
  prm.b_emu = b_emu; prm.b_elv = b_elv; prm.b_pmu = b_pmu; prm.b_plv = b_plv;
  prm.b_pz = b_pz; prm.b_d1 = b_d1; prm.b_d2 = b_d2;
  prm.b_dmu = b_dmu; prm.b_dlv = b_dlv;
  prm.eps = eps; prm.x = x;
  prm.h0a = h0a; prm.h0b = h0b; prm.h1a = h1a; prm.h1b = h1b;
  prm.accf = accf;

  k_vrnn16<<<dim3(16), dim3(256), 0, stream>>>(prm);
  k_final<<<dim3(1), dim3(64), 0, stream>>>(accf, (float*)d_out);
}